// Round 6
// baseline (205.220 us; speedup 1.0000x reference)
//
#include <hip/hip_runtime.h>
#include <math.h>
#include <float.h>

#define B_ 64
#define T_ 100
#define N_ 20000
#define NQ (B_ * T_)              // 6400 queries
#define NCHUNKS 250
#define CHUNK (N_ / NCHUNKS)      // 80 points per chunk
#define CPAIRS (CHUNK / 2)        // 40 pairs per chunk
#define GROUPS (CPAIRS / 2)       // 20 groups (4 points) per chunk
#define QG 640                    // queries per block (amortizes LDS broadcast)
#define NQG (NQ / QG)             // 10
#define QPT 10                    // queries per thread
#define NTHR 64                   // one wave per block
#define NBLOCKS (NQG * NCHUNKS)   // 2500

typedef float f2 __attribute__((ext_vector_type(2)));
typedef float f4 __attribute__((ext_vector_type(4)));
typedef unsigned long long u64;

// ws layout (single 0xFF memset covers all of it):
//   keys    u64[NQ]   packed (sortable(e)<<32)|idx, atomicMin; init 0xFF..F
//   counter u32       fan-in ticket; init 0xFFFFFFFF -> i-th incrementer
//                     gets ticket i-1, so last block <=> ticket == NBLOCKS-2
#define KEYS_BYTES (NQ * sizeof(u64))
#define CTR_OFF    KEYS_BYTES

// Map f32 -> u32 preserving < order for all finite values (incl. negatives).
__device__ __forceinline__ unsigned int f32_sortable(float f) {
    unsigned int u = __float_as_uint(f);
    return ((int)u >= 0) ? (u | 0x80000000u) : ~u;
}

// ---------------------------------------------------------------------------
// Fused kernel. Block = (query-group of 640, chunk of 80 points).
// Rigid transforms preserve distance: |w - R^T(g-t)| = |(Rw+t)-g|, so the NN
// search runs in the global frame (batch-independent point data).
// Main loop tracks BOTH best-e and exact winning index branchlessly -> the
// old divergent-LDS resolve tail (32-way bank conflicts, ~21us chip-wide) is
// gone. Last-finishing block (ticket fan-in, device-scope) runs the epilogue.
// ---------------------------------------------------------------------------
__global__ __launch_bounds__(NTHR) void k_fused(
    const float* __restrict__ poses,      // [B,4,4]
    const float* __restrict__ wpts,       // [B,T,3]
    const float* __restrict__ boundary,   // [4,N]
    const float* __restrict__ bnorm,      // [3,N]
    u64* __restrict__ keys,               // [NQ]
    unsigned int* __restrict__ counter,
    float* __restrict__ out)
{
    __shared__ f4 sh[GROUPS][4];          // [g]: {a0,b0,a1,b1}
                                          // a={-2x0,-2x1,-2y0,-2y1}
                                          // b={-2z0,-2z1, p2_0, p2_1}
    __shared__ float sposes[B_ * 16];     // all poses, 4 KB
    __shared__ unsigned int sticket;

    const int bx   = blockIdx.x;
    const int qg   = bx / NCHUNKS;
    const int c    = bx - qg * NCHUNKS;
    const int base = c * CHUNK;
    const int tid  = threadIdx.x;

    // ---- stage all poses into LDS (coalesced f4 copy, 4 per thread) ----
    {
        const f4* pg  = (const f4*)poses;
        f4*       sp4 = (f4*)sposes;
#pragma unroll
        for (int j = 0; j < 4; ++j)
            sp4[j * 64 + tid] = pg[j * 64 + tid];
    }

    // ---- stage chunk: pair p -> group p>>1, slot (p&1)*2 ----
    if (tid < CPAIRS) {
        const int n0 = base + 2 * tid;
        const float x0 = boundary[n0],          x1 = boundary[n0 + 1];
        const float y0 = boundary[N_ + n0],     y1 = boundary[N_ + n0 + 1];
        const float z0 = boundary[2 * N_ + n0], z1 = boundary[2 * N_ + n0 + 1];
        f4 a = { -2.f * x0, -2.f * x1, -2.f * y0, -2.f * y1 };
        f4 b = { -2.f * z0, -2.f * z1,
                 x0 * x0 + y0 * y0 + z0 * z0,
                 x1 * x1 + y1 * y1 + z1 * z1 };
        sh[tid >> 1][(tid & 1) * 2 + 0] = a;
        sh[tid >> 1][(tid & 1) * 2 + 1] = b;
    }
    __syncthreads();

    // ---- per-thread queries: global waypoint q = R w + t ----
    float qx[QPT], qy[QPT], qz[QPT];
#pragma unroll
    for (int k = 0; k < QPT; ++k) {
        const int i = qg * QG + k * 64 + tid;
        const int b = i / T_;
        const float* P = sposes + b * 16;
        const float* W = wpts + i * 3;
        const float wx = W[0], wy = W[1], wz = W[2];
        qx[k] = P[0] * wx + P[1] * wy + P[2]  * wz + P[3];
        qy[k] = P[4] * wx + P[5] * wy + P[6]  * wz + P[7];
        qz[k] = P[8] * wx + P[9] * wy + P[10] * wz + P[11];
    }

    float beste[QPT];
    int   bidx[QPT];
#pragma unroll
    for (int k = 0; k < QPT; ++k) { beste[k] = FLT_MAX; bidx[k] = 0; }

#pragma unroll 4
    for (int g = 0; g < GROUPS; ++g) {
        const f4 A0 = sh[g][0], B0 = sh[g][1];
        const f4 A1 = sh[g][2], B1 = sh[g][3];
        const f2 mx0 = { A0.x, A0.y }, my0 = { A0.z, A0.w };
        const f2 mz0 = { B0.x, B0.y }, p20 = { B0.z, B0.w };
        const f2 mx1 = { A1.x, A1.y }, my1 = { A1.z, A1.w };
        const f2 mz1 = { B1.x, B1.y }, p21 = { B1.z, B1.w };
        const int gbase = base + 4 * g;

#pragma unroll
        for (int k = 0; k < QPT; ++k) {
            const f2 vx = { qx[k], qx[k] };
            const f2 vy = { qy[k], qy[k] };
            const f2 vz = { qz[k], qz[k] };
            // e = p2 - 2 q.g  (3 packed FMAs per 2 points)
            f2 eA = __builtin_elementwise_fma(mx0, vx,
                    __builtin_elementwise_fma(my0, vy,
                    __builtin_elementwise_fma(mz0, vz, p20)));
            f2 eB = __builtin_elementwise_fma(mx1, vx,
                    __builtin_elementwise_fma(my1, vy,
                    __builtin_elementwise_fma(mz1, vz, p21)));
            f2 m2 = __builtin_elementwise_min(eA, eB);
            float m = fminf(m2.x, m2.y);
            // exact slot, first-occurrence on ties (branchless)
            int slot = (m == eA.x) ? 0 : (m == eA.y) ? 1
                     : (m == eB.x) ? 2 : 3;
            const bool cc = m < beste[k];
            beste[k] = cc ? m : beste[k];
            bidx[k]  = cc ? (gbase + slot) : bidx[k];
        }
    }

    // ---- land partials: one u64 atomicMin per (query, chunk) ----
#pragma unroll
    for (int k = 0; k < QPT; ++k) {
        const u64 key = ((u64)f32_sortable(beste[k]) << 32)
                      | (unsigned)bidx[k];
        atomicMin(&keys[qg * QG + k * 64 + tid], key);
    }

    // ---- fan-in: last block to finish runs the epilogue ----
    __syncthreads();                        // drain this block's atomics
    if (tid == 0) {
        __threadfence();                    // release: atomics visible
        sticket = atomicAdd(counter, 1u);   // init 0xFFFFFFFF -> ticket i-1
    }
    __syncthreads();
    if (sticket != (unsigned)(NBLOCKS - 2)) return;   // not last -> done

    // Last block: all 2500 tickets taken => all atomicMins complete.
    __threadfence();                        // acquire side

    // Epilogue: dots = (q - g) . n (rotation-invariant == reference's
    // local-frame dot), ExpRelu, mean. 100 iterations over 6400 queries.
    float acc = 0.0f;
    for (int i = tid; i < NQ; i += NTHR) {
        const u64 key = __hip_atomic_load(&keys[i], __ATOMIC_RELAXED,
                                          __HIP_MEMORY_SCOPE_AGENT);
        const int bi = (int)(unsigned)(key & 0xFFFFFFFFull);

        const int b = i / T_;
        const float* P = sposes + b * 16;   // poses already staged in LDS
        const float* W = wpts + i * 3;
        const float wx = W[0], wy = W[1], wz = W[2];
        const float qx2 = P[0] * wx + P[1] * wy + P[2]  * wz + P[3];
        const float qy2 = P[4] * wx + P[5] * wy + P[6]  * wz + P[7];
        const float qz2 = P[8] * wx + P[9] * wy + P[10] * wz + P[11];

        const float gx = boundary[bi];
        const float gy = boundary[N_ + bi];
        const float gz = boundary[2 * N_ + bi];
        const float nx = bnorm[bi];
        const float ny = bnorm[N_ + bi];
        const float nz = bnorm[2 * N_ + bi];

        const float dots = (qx2 - gx) * nx + (qy2 - gy) * ny + (qz2 - gz) * nz;
        // ExpRelu: alpha=1, beta=0.5
        acc += (dots > 0.0f) ? (dots + 1.0f) : expf(0.5f * dots);
    }
    // wave-level sum across 64 lanes
#pragma unroll
    for (int off = 32; off > 0; off >>= 1)
        acc += __shfl_down(acc, off, 64);
    if (tid == 0) out[0] = acc * (1.0f / (float)NQ);
}

extern "C" void kernel_launch(void* const* d_in, const int* in_sizes, int n_in,
                              void* d_out, int out_size, void* d_ws, size_t ws_size,
                              hipStream_t stream) {
    const float* poses    = (const float*)d_in[0];
    const float* wpts     = (const float*)d_in[1];
    const float* boundary = (const float*)d_in[2];
    const float* bnorm    = (const float*)d_in[3];
    float* out = (float*)d_out;

    u64*          keys    = (u64*)d_ws;
    unsigned int* counter = (unsigned int*)((char*)d_ws + CTR_OFF);

    // One fill covers keys (0xFF..F = u64 max, loses to any real key) AND the
    // ticket counter (0xFFFFFFFF; i-th incrementer gets i-1, last == grid-2).
    hipMemsetAsync(d_ws, 0xFF, KEYS_BYTES + sizeof(unsigned int), stream);

    k_fused<<<NBLOCKS, NTHR, 0, stream>>>(
        poses, wpts, boundary, bnorm, keys, counter, out);
}

// Round 7
// 123.633 us; speedup vs baseline: 1.6599x; 1.6599x over previous
//
#include <hip/hip_runtime.h>
#include <math.h>
#include <float.h>

#define B_ 64
#define T_ 100
#define N_ 20000
#define NQ (B_ * T_)              // 6400 queries
#define NCHUNKS 250
#define CHUNK (N_ / NCHUNKS)      // 80 points per chunk
#define CPAIRS (CHUNK / 2)        // 40 pairs per chunk
#define GROUPS (CPAIRS / 2)       // 20 groups (4 points) per chunk
#define QG 640                    // queries per block (amortizes LDS broadcast)
#define NQG (NQ / QG)             // 10
#define QPT 10                    // queries per thread
#define NTHR 64                   // one wave per block
#define NBLOCKS (NQG * NCHUNKS)   // 2500
#define K2_BLOCKS (NQ / 256)      // 25

typedef float f2 __attribute__((ext_vector_type(2)));
typedef float f4 __attribute__((ext_vector_type(4)));
typedef unsigned long long u64;

// ws layout:
//   pk   u64[NCHUNKS][NQ]  12.8 MB   partial keys (sortable(e)<<32)|idx
//   bsum float[K2_BLOCKS]            per-k2-block partial sums
// No init needed: k1 writes every pk slot, k2 writes every bsum slot.
#define PK_BYTES  ((size_t)NCHUNKS * NQ * sizeof(u64))
#define BSUM_OFF  PK_BYTES

// Map f32 -> u32 preserving < order for all finite values (incl. negatives).
__device__ __forceinline__ unsigned int f32_sortable(float f) {
    unsigned int u = __float_as_uint(f);
    return ((int)u >= 0) ? (u | 0x80000000u) : ~u;
}

// ---------------------------------------------------------------------------
// Kernel 1: global-frame partial 1-NN. Block = (query-group of 640, chunk of
// 80 points). Rigid transforms preserve distance: |w - R^T(g-t)| = |(Rw+t)-g|,
// so the NN search runs in the global frame (batch-independent point data).
// Main loop tracks best-e AND exact winning index branchlessly (no divergent
// LDS resolve tail). Partials land as plain coalesced u64 stores -- no
// atomics, no fences (R6's per-block device-scope fence cost 2500 L2
// writebacks and serialized the grid). Inter-kernel release handles
// cross-XCD visibility.
// ---------------------------------------------------------------------------
__global__ __launch_bounds__(NTHR) void k1_nn(
    const float* __restrict__ poses,      // [B,4,4]
    const float* __restrict__ wpts,       // [B,T,3]
    const float* __restrict__ boundary,   // [4,N]
    u64* __restrict__ pk)                 // [NCHUNKS][NQ]
{
    __shared__ f4 sh[GROUPS][4];          // [g]: {a0,b0,a1,b1}
                                          // a={-2x0,-2x1,-2y0,-2y1}
                                          // b={-2z0,-2z1, p2_0, p2_1}
    __shared__ float sposes[B_ * 16];     // all poses, 4 KB

    const int bx   = blockIdx.x;
    const int qg   = bx / NCHUNKS;
    const int c    = bx - qg * NCHUNKS;
    const int base = c * CHUNK;
    const int tid  = threadIdx.x;

    // ---- stage all poses into LDS (coalesced f4 copy, 4 per thread) ----
    {
        const f4* pg  = (const f4*)poses;
        f4*       sp4 = (f4*)sposes;
#pragma unroll
        for (int j = 0; j < 4; ++j)
            sp4[j * 64 + tid] = pg[j * 64 + tid];
    }

    // ---- stage chunk: pair p -> group p>>1, slot (p&1)*2 ----
    if (tid < CPAIRS) {
        const int n0 = base + 2 * tid;
        const float x0 = boundary[n0],          x1 = boundary[n0 + 1];
        const float y0 = boundary[N_ + n0],     y1 = boundary[N_ + n0 + 1];
        const float z0 = boundary[2 * N_ + n0], z1 = boundary[2 * N_ + n0 + 1];
        f4 a = { -2.f * x0, -2.f * x1, -2.f * y0, -2.f * y1 };
        f4 b = { -2.f * z0, -2.f * z1,
                 x0 * x0 + y0 * y0 + z0 * z0,
                 x1 * x1 + y1 * y1 + z1 * z1 };
        sh[tid >> 1][(tid & 1) * 2 + 0] = a;
        sh[tid >> 1][(tid & 1) * 2 + 1] = b;
    }
    __syncthreads();

    // ---- per-thread queries: global waypoint q = R w + t ----
    float qx[QPT], qy[QPT], qz[QPT];
#pragma unroll
    for (int k = 0; k < QPT; ++k) {
        const int i = qg * QG + k * 64 + tid;
        const int b = i / T_;
        const float* P = sposes + b * 16;
        const float* W = wpts + i * 3;
        const float wx = W[0], wy = W[1], wz = W[2];
        qx[k] = P[0] * wx + P[1] * wy + P[2]  * wz + P[3];
        qy[k] = P[4] * wx + P[5] * wy + P[6]  * wz + P[7];
        qz[k] = P[8] * wx + P[9] * wy + P[10] * wz + P[11];
    }

    float beste[QPT];
    int   bidx[QPT];
#pragma unroll
    for (int k = 0; k < QPT; ++k) { beste[k] = FLT_MAX; bidx[k] = 0; }

#pragma unroll 4
    for (int g = 0; g < GROUPS; ++g) {
        const f4 A0 = sh[g][0], B0 = sh[g][1];
        const f4 A1 = sh[g][2], B1 = sh[g][3];
        const f2 mx0 = { A0.x, A0.y }, my0 = { A0.z, A0.w };
        const f2 mz0 = { B0.x, B0.y }, p20 = { B0.z, B0.w };
        const f2 mx1 = { A1.x, A1.y }, my1 = { A1.z, A1.w };
        const f2 mz1 = { B1.x, B1.y }, p21 = { B1.z, B1.w };
        const int gbase = base + 4 * g;

#pragma unroll
        for (int k = 0; k < QPT; ++k) {
            const f2 vx = { qx[k], qx[k] };
            const f2 vy = { qy[k], qy[k] };
            const f2 vz = { qz[k], qz[k] };
            // e = p2 - 2 q.g  (3 packed FMAs per 2 points)
            f2 eA = __builtin_elementwise_fma(mx0, vx,
                    __builtin_elementwise_fma(my0, vy,
                    __builtin_elementwise_fma(mz0, vz, p20)));
            f2 eB = __builtin_elementwise_fma(mx1, vx,
                    __builtin_elementwise_fma(my1, vy,
                    __builtin_elementwise_fma(mz1, vz, p21)));
            f2 m2 = __builtin_elementwise_min(eA, eB);
            float m = fminf(m2.x, m2.y);
            // exact slot, first-occurrence on ties (branchless)
            int slot = (m == eA.x) ? 0 : (m == eA.y) ? 1
                     : (m == eB.x) ? 2 : 3;
            const bool cc = m < beste[k];
            beste[k] = cc ? m : beste[k];
            bidx[k]  = cc ? (gbase + slot) : bidx[k];
        }
    }

    // ---- land partials: coalesced u64 stores (512 B per wave-store) ----
#pragma unroll
    for (int k = 0; k < QPT; ++k) {
        const u64 key = ((u64)f32_sortable(beste[k]) << 32)
                      | (unsigned)bidx[k];
        pk[(size_t)c * NQ + qg * QG + k * 64 + tid] = key;
    }
}

// ---------------------------------------------------------------------------
// Kernel 2: per query, u64-min over the 250 chunk partials (ascending c ->
// packed idx in low bits preserves first-occurrence ties), then global-frame
// epilogue: dots = (q - g).n (rotation-invariant == reference's local-frame
// dot), ExpRelu, block-reduce, write per-block partial sum (no atomics).
// ---------------------------------------------------------------------------
__global__ __launch_bounds__(256) void k2_reduce(
    const float* __restrict__ poses,
    const float* __restrict__ wpts,
    const float* __restrict__ boundary,   // [4,N]
    const float* __restrict__ bnorm,      // [3,N]
    const u64* __restrict__ pk,
    float* __restrict__ bsum)             // [K2_BLOCKS]
{
    const int tid = threadIdx.x;
    const int i = blockIdx.x * 256 + tid;     // i in [0, 6400)

    u64 best = pk[i];                         // c = 0
#pragma unroll 10
    for (int c = 1; c < NCHUNKS; ++c) {
        const u64 v = pk[(size_t)c * NQ + i];
        best = (v < best) ? v : best;
    }
    const int bi = (int)(unsigned)(best & 0xFFFFFFFFull);

    const int b = i / T_;
    const float* P = poses + b * 16;
    const float* W = wpts + i * 3;
    const float wx = W[0], wy = W[1], wz = W[2];
    const float qx = P[0] * wx + P[1] * wy + P[2]  * wz + P[3];
    const float qy = P[4] * wx + P[5] * wy + P[6]  * wz + P[7];
    const float qz = P[8] * wx + P[9] * wy + P[10] * wz + P[11];

    const float gx = boundary[bi], gy = boundary[N_ + bi], gz = boundary[2 * N_ + bi];
    const float nx = bnorm[bi],    ny = bnorm[N_ + bi],    nz = bnorm[2 * N_ + bi];

    const float dots = (qx - gx) * nx + (qy - gy) * ny + (qz - gz) * nz;
    // ExpRelu: alpha=1, beta=0.5; pre-scaled for the final mean
    float val = (dots > 0.0f) ? (dots + 1.0f) : expf(0.5f * dots);
    val *= (1.0f / (float)NQ);

    __shared__ float red[256];
    red[tid] = val;
    __syncthreads();
#pragma unroll
    for (int s = 128; s > 0; s >>= 1) {
        if (tid < s) red[tid] += red[tid + s];
        __syncthreads();
    }
    if (tid == 0) bsum[blockIdx.x] = red[0];
}

// ---------------------------------------------------------------------------
// Kernel 3: final sum of the 25 block partials.
// ---------------------------------------------------------------------------
__global__ __launch_bounds__(64) void k3_final(
    const float* __restrict__ bsum,
    float* __restrict__ out)
{
    const int tid = threadIdx.x;
    float v = (tid < K2_BLOCKS) ? bsum[tid] : 0.0f;
#pragma unroll
    for (int off = 32; off > 0; off >>= 1)
        v += __shfl_down(v, off, 64);
    if (tid == 0) out[0] = v;
}

extern "C" void kernel_launch(void* const* d_in, const int* in_sizes, int n_in,
                              void* d_out, int out_size, void* d_ws, size_t ws_size,
                              hipStream_t stream) {
    const float* poses    = (const float*)d_in[0];
    const float* wpts     = (const float*)d_in[1];
    const float* boundary = (const float*)d_in[2];
    const float* bnorm    = (const float*)d_in[3];
    float* out = (float*)d_out;

    u64*   pk   = (u64*)d_ws;
    float* bsum = (float*)((char*)d_ws + BSUM_OFF);

    k1_nn<<<NBLOCKS, NTHR, 0, stream>>>(poses, wpts, boundary, pk);
    k2_reduce<<<K2_BLOCKS, 256, 0, stream>>>(
        poses, wpts, boundary, bnorm, pk, bsum);
    k3_final<<<1, 64, 0, stream>>>(bsum, out);
}